// Round 10
// baseline (567.241 us; speedup 1.0000x reference)
//
#include <hip/hip_runtime.h>
#include <cstdint>

// LatentFactorPooling on MI355X.
// x: (64,256,64,44) fp32, basis: (4,16,256) fp32.
// out: tokens (64,256,64) fp32 then pres (64,64) fp32.
//
// Round-13: forced software pipeline in k_route. Round-9 counters showed
// VGPR_Count=40 < the ~52 needed for the source-level ping-pong -> hipcc
// had SUNK the prefetch loads back into the consumes (explains why 6
// structural variants all measured 105-112us: the pipeline never existed).
// Fix: depth-4 rotating x-prefetch with __builtin_amdgcn_sched_barrier(0)
// fences so loads cannot sink past the following consume region.
//
// Workspace layout (floats):
//   lbn_ws     [0,16384)             normalized basis, [g][c][k]
//   invden_ws  [16384,20480)         1/max(sum_p supp,1e-6) per (s,k)
//   presraw    [20480,24576)         unnormalized presence per (s,k)
//   supp_pk    [2908160,5791744)     supp, [s][p][k]  (tokens kernel)

#define C_ 256
#define W_ 44
#define P_ 704          // 16*44 positions per stripe
#define CH_STRIDE 2816  // 64*44
#define NB_STRIDE 720896 // 256*2816
#define TOPK_ 88
#define GATE_ 0.05f
#define EPS_ 1e-6f

// DPP wave-wide shifts: lane i <- lane i-1 (shr) / i+1 (shl), bound_ctrl
// zero-fills the edge lane. VALU pipe.
#define DPP_WAVE_SHL1 0x130
#define DPP_WAVE_SHR1 0x138
__device__ __forceinline__ float dpp_from_left(float v) {   // lane l gets v[l-1], lane0 -> 0
  return __int_as_float(__builtin_amdgcn_update_dpp(
      0, __float_as_int(v), DPP_WAVE_SHR1, 0xF, 0xF, true));
}
__device__ __forceinline__ float dpp_from_right(float v) {  // lane l gets v[l+1], lane63 -> 0
  return __int_as_float(__builtin_amdgcn_update_dpp(
      0, __float_as_int(v), DPP_WAVE_SHL1, 0xF, 0xF, true));
}

// ---------------- kernel A: normalize latent basis ----------------
__global__ __launch_bounds__(256) void k_norm_basis(const float* __restrict__ lb,
                                                    float* __restrict__ lbn) {
  int gk = blockIdx.x;           // g*16+k
  int t = threadIdx.x;           // channel
  float v = lb[gk * 256 + t];
  float ss = v * v;
  #pragma unroll
  for (int off = 32; off >= 1; off >>= 1) ss += __shfl_xor(ss, off);
  __shared__ float red[4];
  if ((t & 63) == 0) red[t >> 6] = ss;
  __syncthreads();
  float tot = red[0] + red[1] + red[2] + red[3];
  float scale = 1.f / fmaxf(sqrtf(tot), 1e-12f);
  int g = gk >> 4, k = gk & 15;
  lbn[((g * 256 + t) << 4) + k] = v * scale;   // [g][c][k]
}

// ---------------- kernel B: MONOLITH routing, forced depth-4 pipeline --------
// One block per stripe, 1024 threads, wave w = stripe row w, lanes 0..43
// active. Main loop: barrier-free, LDS-free (DPP horizontal exchange, basis
// via wave-uniform scalar loads), depth-4 rotating prefetch enforced by
// sched_barrier(0) fences. Epilogue (verified rounds 5-9): 3x3 pool via LDS,
// energy gate, softmax, supp, invden, fused exact top-88 radix select.
#define LOADX(X, cbase)                                                \
  { _Pragma("unroll")                                                  \
    for (int j_ = 0; j_ < 4; j_++) {                                   \
      const size_t o_ = (size_t)((cbase) + j_) * CH_STRIDE;            \
      X[j_] = xm[o_]; X[j_ + 4] = xb[o_]; X[j_ + 8] = xp[o_];          \
    } }

#define CONS_GRP(X, cbase)                                             \
  { _Pragma("unroll")                                                  \
    for (int j_ = 0; j_ < 4; j_++) {                                   \
      float a  = act ? X[j_ + 4] : 0.f;                                \
      float am_ = (act && hm) ? X[j_] : 0.f;                           \
      float ap_ = (act && hp) ? X[j_ + 8] : 0.f;                       \
      float vs = am_ + a + ap_;                                        \
      float lf = dpp_from_left(vs);                                    \
      float rt = dpp_from_right(vs);                                   \
      float win = lf + vs + rt;                                        \
      pw2 = fmaf(win, win, pw2);                                       \
      sq  = fmaf(a, a, sq);                                            \
      const int co_ = __builtin_amdgcn_readfirstlane(((cbase) + j_) << 4); \
      const float4* wp4 = (const float4*)(lbb + co_);                  \
      float4 w0 = wp4[0], w1 = wp4[1], w2 = wp4[2], w3 = wp4[3];       \
      rawdot[0]  = fmaf(a, w0.x, rawdot[0]);  rawdot[1]  = fmaf(a, w0.y, rawdot[1]);  \
      rawdot[2]  = fmaf(a, w0.z, rawdot[2]);  rawdot[3]  = fmaf(a, w0.w, rawdot[3]);  \
      rawdot[4]  = fmaf(a, w1.x, rawdot[4]);  rawdot[5]  = fmaf(a, w1.y, rawdot[5]);  \
      rawdot[6]  = fmaf(a, w1.z, rawdot[6]);  rawdot[7]  = fmaf(a, w1.w, rawdot[7]);  \
      rawdot[8]  = fmaf(a, w2.x, rawdot[8]);  rawdot[9]  = fmaf(a, w2.y, rawdot[9]);  \
      rawdot[10] = fmaf(a, w2.z, rawdot[10]); rawdot[11] = fmaf(a, w2.w, rawdot[11]); \
      rawdot[12] = fmaf(a, w3.x, rawdot[12]); rawdot[13] = fmaf(a, w3.y, rawdot[13]); \
      rawdot[14] = fmaf(a, w3.z, rawdot[14]); rawdot[15] = fmaf(a, w3.w, rawdot[15]); \
    } }

__global__ __launch_bounds__(1024, 4) void k_route(const float* __restrict__ x,
                                                   const float* __restrict__ lbn,
                                                   float* __restrict__ supp_pk,
                                                   float* __restrict__ invden_ws,
                                                   float* __restrict__ presraw) {
  __shared__ float rsl[11264];          // rawdot [k][704], then supp [k][704]; 44 KB
  __shared__ uint32_t hist_l[16 * 256]; // per-wave radix histograms, 16 KB
  __shared__ float redA[16];
  __shared__ float redB[16];
  __shared__ float redM[2];
  __shared__ float red2[16 * 16];

  const int tid = threadIdx.x;
  const int w = tid >> 6;          // row
  const int l = tid & 63;          // col
  const bool act = (l < 44);
  const int s = blockIdx.x, n = s >> 2, g = s & 3;
  const int p = w * 44 + l;

  const int lsafe = act ? l : 0;   // address clamp
  const float* xb = x + (size_t)n * NB_STRIDE + (g * 16 + w) * 44 + lsafe;
  const float* xm = xb + ((w > 0)  ? -44 : 0);   // clamped row addresses
  const float* xp = xb + ((w < 15) ?  44 : 0);
  const bool hm = (w > 0), hp = (w < 15);

  // wave-uniform basis base for this group: 256ch x 16k slice
  const float* lbb = lbn + (g << 12);

  float rawdot[16];
  #pragma unroll
  for (int k = 0; k < 16; k++) rawdot[k] = 0.f;
  float sq = 0.f, pw2 = 0.f;

  float X0[12], X1[12], X2[12], X3[12];
  LOADX(X0, 0)
  LOADX(X1, 4)
  LOADX(X2, 8)
  LOADX(X3, 12)
  __builtin_amdgcn_sched_barrier(0);

  for (int c = 0; c < 256; c += 16) {
    CONS_GRP(X0, c)
    if (c + 16 < 256) { LOADX(X0, c + 16) }
    __builtin_amdgcn_sched_barrier(0);
    CONS_GRP(X1, c + 4)
    if (c + 20 < 256) { LOADX(X1, c + 20) }
    __builtin_amdgcn_sched_barrier(0);
    CONS_GRP(X2, c + 8)
    if (c + 24 < 256) { LOADX(X2, c + 24) }
    __builtin_amdgcn_sched_barrier(0);
    CONS_GRP(X3, c + 12)
    if (c + 28 < 256) { LOADX(X3, c + 28) }
    __builtin_amdgcn_sched_barrier(0);
  }

  // ---- epilogue: pool, gate, softmax, supp, invden, fused topk ----
  if (act) {
    #pragma unroll
    for (int k = 0; k < 16; k++) rsl[k * 704 + p] = rawdot[k];
  }
  __syncthreads();   // rsl ready

  // 3x3 pool of rawdot (linearity: pool(raw).basis == pool(raw.basis))
  float pd[16];
  #pragma unroll
  for (int k = 0; k < 16; k++) pd[k] = 0.f;
  if (act) {
    #pragma unroll
    for (int dy = -1; dy <= 1; dy++) {
      int yy = w + dy;
      if (yy < 0 || yy > 15) continue;
      #pragma unroll
      for (int dx = -1; dx <= 1; dx++) {
        int xx = l + dx;
        if (xx < 0 || xx > 43) continue;
        int pp = yy * 44 + xx;
        #pragma unroll
        for (int k = 0; k < 16; k++) pd[k] += rsl[k * 704 + pp];
      }
    }
  }

  // stripe-wide energy max
  float e_raw = sq * (1.f / 256.f);            // inactive lanes: 0
  float m = e_raw;
  #pragma unroll
  for (int off = 32; off >= 1; off >>= 1) m = fmaxf(m, __shfl_xor(m, off));
  if (l == 0) redA[w] = m;
  __syncthreads();                             // (also: all rsl pool-reads done)
  if (tid == 0) {
    float mm = redA[0];
    for (int w2 = 1; w2 < 16; w2++) mm = fmaxf(mm, redA[w2]);
    redM[0] = mm;
  }
  __syncthreads();
  float M = fmaxf(redM[0], EPS_);
  float e = e_raw / M;
  float am = (e > GATE_) ? 1.f : 0.f;
  float fb = (e_raw > 0.f) ? 1.f : 0.f;
  float a = am;
  #pragma unroll
  for (int off = 32; off >= 1; off >>= 1) a += __shfl_xor(a, off);
  if (l == 0) redB[w] = a;
  __syncthreads();
  if (tid == 0) {
    float sm = 0.f;
    for (int w2 = 0; w2 < 16; w2++) sm += redB[w2];
    redM[1] = sm;
  }
  __syncthreads();
  if (redM[1] <= 0.f) am = fb;

  float pnorm = sqrtf(pw2) * (1.f / 9.f);      // ||pooled||
  float invn = 1.f / fmaxf(pnorm, 1e-12f);
  float scl = invn * (8.f / 9.f);              // /9 pool, /0.125 temp
  float li[16];
  float mx = -1e30f;
  #pragma unroll
  for (int k = 0; k < 16; k++) { li[k] = pd[k] * scl; mx = fmaxf(mx, li[k]); }
  float ssum = 0.f;
  #pragma unroll
  for (int k = 0; k < 16; k++) { li[k] = __expf(li[k] - mx); ssum += li[k]; }
  float rs2 = am / ssum;
  float supp[16];
  #pragma unroll
  for (int k = 0; k < 16; k++) supp[k] = li[k] * rs2;

  // global supp in [p][k] layout for k_tokens
  if (act) {
    float* spk = supp_pk + ((size_t)s * 704 + p) * 16;
    #pragma unroll
    for (int kq = 0; kq < 4; kq++)
      ((float4*)spk)[kq] = make_float4(supp[kq*4+0], supp[kq*4+1],
                                       supp[kq*4+2], supp[kq*4+3]);
  }

  // per-k denominators (inactive lanes contribute 0)
  #pragma unroll
  for (int k = 0; k < 16; k++) {
    float v2 = act ? supp[k] : 0.f;
    #pragma unroll
    for (int off = 32; off >= 1; off >>= 1) v2 += __shfl_xor(v2, off);
    if (l == 0) red2[w * 16 + k] = v2;
  }
  __syncthreads();
  if (tid < 16) {
    float den = 0.f;
    for (int w2 = 0; w2 < 16; w2++) den += red2[w2 * 16 + tid];
    invden_ws[s * 16 + tid] = 1.f / fmaxf(den, EPS_);
  }

  // ---- fused exact top-88 mean (per-wave radix select) ----
  // overwrite rsl with supp [k][704] (all pool reads completed before the
  // redA barrier above)
  if (act) {
    #pragma unroll
    for (int k = 0; k < 16; k++) rsl[k * 704 + p] = supp[k];
  }
  __syncthreads();   // supp in LDS visible to all waves

  {
    const int k = w;               // wave w owns latent k
    uint32_t key[11];
    #pragma unroll
    for (int j = 0; j < 11; j++)
      key[j] = __float_as_uint(rsl[k * 704 + l + 64 * j]);  // supp>=0 -> monotone bits
    uint32_t* h = &hist_l[w * 256];
    uint32_t prefix = 0, remaining = TOPK_;
    #pragma unroll
    for (int b = 3; b >= 0; b--) {
      const int shift = b * 8;
      *(uint4*)&h[l * 4] = make_uint4(0u, 0u, 0u, 0u);
      uint32_t mhi = (b == 3) ? 0u : (0xFFFFFFFFu << (shift + 8));
      #pragma unroll
      for (int j = 0; j < 11; j++)
        if ((key[j] & mhi) == (prefix & mhi))
          atomicAdd(&h[(key[j] >> shift) & 255u], 1u);
      uint4 bn = *(uint4*)&h[l * 4];
      uint32_t T = bn.x + bn.y + bn.z + bn.w;
      uint32_t inc = T;
      #pragma unroll
      for (int off = 1; off < 64; off <<= 1) {
        uint32_t o = (uint32_t)__shfl_down((int)inc, off);
        if (l + off < 64) inc += o;
      }                              // inc = sum over lanes >= l
      uint32_t excl = inc - T;       // lanes > l
      uint32_t g3 = excl + bn.w, g2 = g3 + bn.z, g1 = g2 + bn.y, g0 = g1 + bn.x;
      uint32_t pk = 0u;
      if (g0 >= remaining && g1 < remaining) pk = ((uint32_t)(4*l+0) << 16) | (remaining - g1);
      if (g1 >= remaining && g2 < remaining) pk = ((uint32_t)(4*l+1) << 16) | (remaining - g2);
      if (g2 >= remaining && g3 < remaining) pk = ((uint32_t)(4*l+2) << 16) | (remaining - g3);
      if (g3 >= remaining && excl < remaining) pk = ((uint32_t)(4*l+3) << 16) | (remaining - excl);
      #pragma unroll
      for (int off = 32; off >= 1; off >>= 1) pk |= (uint32_t)__shfl_xor((int)pk, off);
      prefix |= ((pk >> 16) & 255u) << shift;
      remaining = pk & 0xFFFFu;
    }
    float tf = __uint_as_float(prefix);
    float sgt = 0.f; uint32_t cgt = 0u;
    #pragma unroll
    for (int j = 0; j < 11; j++)
      if (key[j] > prefix) { sgt += __uint_as_float(key[j]); cgt++; }
    #pragma unroll
    for (int off = 32; off >= 1; off >>= 1) {
      sgt += __shfl_xor(sgt, off);
      cgt += (uint32_t)__shfl_xor((int)cgt, off);
    }
    if (l == 0)
      presraw[s * 16 + k] = (sgt + (float)(TOPK_ - cgt) * tf) * (1.f / (float)TOPK_);
  }
}

// ---------------- kernel 3: tokens GEMM, channel-split (2 blocks/stripe) ----------------
__global__ __launch_bounds__(512, 4) void k_tokens(const float* __restrict__ x,
                                                   const float* __restrict__ supp_pk,
                                                   const float* __restrict__ invden,
                                                   float* __restrict__ out) {
  __shared__ float xl[4096];   // 128ch x 32pos; reused for quarter-reduce
  const int tid = threadIdx.x;
  const int bid = blockIdx.x;
  const int s = bid >> 1, chalf = bid & 1;
  const int n = s >> 2, g = s & 3;
  const int cl = tid & 127;               // local channel
  const int q = tid >> 7;                 // position quarter (wave-uniform)
  const int sblk = s * (704 * 16);

  const float* xs = x + (size_t)n * NB_STRIDE + (size_t)(chalf * 128) * CH_STRIDE + g * P_;

  const int li0 = tid, li1 = tid + 512;
  const int lc0 = li0 >> 3, lj0 = li0 & 7;
  const int lc1 = li1 >> 3, lj1 = li1 & 7;
  const float* gp0 = xs + (size_t)lc0 * CH_STRIDE + lj0 * 4;
  const float* gp1 = xs + (size_t)lc1 * CH_STRIDE + lj1 * 4;
  const int wo0 = lc0 * 32 + ((lj0 * 4) ^ ((lc0 & 7) * 4));
  const int wo1 = lc1 * 32 + ((lj1 * 4) ^ ((lc1 & 7) * 4));

  const int sw = (cl & 7) * 4;
  const int rbase = cl * 32;

  float acc[16];
  #pragma unroll
  for (int k = 0; k < 16; k++) acc[k] = 0.f;

  float4 r0 = *(const float4*)gp0;
  float4 r1 = *(const float4*)gp1;
  *(float4*)&xl[wo0] = r0;
  *(float4*)&xl[wo1] = r1;
  __syncthreads();

  for (int tt = 0; tt < 22; tt++) {
    const int p0 = tt * 32;
    float4 n0, n1;
    if (tt < 21) {
      n0 = *(const float4*)(gp0 + p0 + 32);
      n1 = *(const float4*)(gp1 + p0 + 32);
    }

    #pragma unroll
    for (int jj = 0; jj < 8; jj += 4) {
      const int pp0 = q * 8 + jj;
      float4 xv = *(const float4*)&xl[rbase + (pp0 ^ sw)];
      float xa[4] = {xv.x, xv.y, xv.z, xv.w};
      #pragma unroll
      for (int dj = 0; dj < 4; dj++) {
        int uofs = __builtin_amdgcn_readfirstlane(sblk + (p0 + pp0 + dj) * 16);
        const float4* sp = (const float4*)(supp_pk + uofs);
        float4 s0 = sp[0], s1 = sp[1], s2 = sp[2], s3 = sp[3];
        float a = xa[dj];
        acc[0]  += a * s0.x; acc[1]  += a * s0.y; acc[2]  += a * s0.z; acc[3]  += a * s0.w;
        acc[4]  += a * s1.x; acc[5]  += a * s1.y; acc[6]  += a * s1.z; acc[7]  += a * s1.w;
        acc[8]  += a * s2.x; acc[9]  += a * s2.y; acc[10] += a * s2.z; acc[11] += a * s2.w;
        acc[12] += a * s3.x; acc[13] += a * s3.y; acc[14] += a * s3.z; acc[15] += a * s3.w;
      }
    }

    __syncthreads();
    if (tt < 21) {
      *(float4*)&xl[wo0] = n0;
      *(float4*)&xl[wo1] = n1;
      __syncthreads();
    }
  }

  // quarter-reduce via LDS (xl reused)
  if (q >= 2) {
    float* dst = &xl[((q - 2) * 128 + cl) * 16];
    #pragma unroll
    for (int kq = 0; kq < 4; kq++)
      ((float4*)dst)[kq] = make_float4(acc[kq*4], acc[kq*4+1], acc[kq*4+2], acc[kq*4+3]);
  }
  __syncthreads();
  if (q < 2) {
    const float* src = &xl[(q * 128 + cl) * 16];
    #pragma unroll
    for (int k = 0; k < 16; k++) acc[k] += src[k];
  }
  __syncthreads();
  if (q == 1) {
    float* dst = &xl[cl * 16];
    #pragma unroll
    for (int kq = 0; kq < 4; kq++)
      ((float4*)dst)[kq] = make_float4(acc[kq*4], acc[kq*4+1], acc[kq*4+2], acc[kq*4+3]);
  }
  __syncthreads();
  if (q == 0) {
    const float* src = &xl[cl * 16];
    float* op = out + ((size_t)(n * 256 + chalf * 128 + cl) * 64) + g * 16;
    #pragma unroll
    for (int kq = 0; kq < 4; kq++) {
      int u = __builtin_amdgcn_readfirstlane(s * 16 + kq * 4);
      const float4 iv = *(const float4*)(invden + u);
      float4 o;
      o.x = (acc[kq*4+0] + src[kq*4+0]) * iv.x;
      o.y = (acc[kq*4+1] + src[kq*4+1]) * iv.y;
      o.z = (acc[kq*4+2] + src[kq*4+2]) * iv.z;
      o.w = (acc[kq*4+3] + src[kq*4+3]) * iv.w;
      ((float4*)op)[kq] = o;
    }
  }
}

// ---------------- kernel D: presence normalization ----------------
__global__ __launch_bounds__(64) void k_pres(const float* __restrict__ presraw,
                                             float* __restrict__ out) {
  const int n = blockIdx.x, t = threadIdx.x;
  float v = presraw[n * 64 + t];
  float ssum = v;
  #pragma unroll
  for (int off = 32; off >= 1; off >>= 1) ssum += __shfl_xor(ssum, off);
  out[1048576 + n * 64 + t] = v / fmaxf(ssum, EPS_);
}

extern "C" void kernel_launch(void* const* d_in, const int* in_sizes, int n_in,
                              void* d_out, int out_size, void* d_ws, size_t ws_size,
                              hipStream_t stream) {
  (void)in_sizes; (void)n_in; (void)out_size; (void)ws_size;
  const float* x  = (const float*)d_in[0];
  const float* lb = (const float*)d_in[1];
  float* out = (float*)d_out;
  float* ws = (float*)d_ws;
  float* lbn_ws     = ws;              // 16384 floats
  float* invden_ws  = ws + 16384;      // 4096
  float* presraw_ws = ws + 20480;      // 4096
  float* supp_pk_ws = ws + 2908160;    // 2883584, supp [s][p][k]

  k_norm_basis<<<64, 256, 0, stream>>>(lb, lbn_ws);
  k_route<<<256, 1024, 0, stream>>>(x, lbn_ws, supp_pk_ws, invden_ws, presraw_ws);
  k_tokens<<<512, 512, 0, stream>>>(x, supp_pk_ws, invden_ws, out);
  k_pres<<<64, 64, 0, stream>>>(presraw_ws, out);
}

// Round 11
// 330.336 us; speedup vs baseline: 1.7172x; 1.7172x over previous
//
#include <hip/hip_runtime.h>
#include <cstdint>

// LatentFactorPooling on MI355X.
// x: (64,256,64,44) fp32, basis: (4,16,256) fp32.
// out: tokens (64,256,64) fp32 then pres (64,64) fp32.
//
// Round-14: k_route REVERTED to the round-9/round-12 monolith exactly
// (108us, VGPR=40 — proven; the forced-pipeline round-13 attempt spilled:
// VGPR pinned at 64 for 1024-thr blocks, WRITE_SIZE 26->338MB scratch,
// 3x slower). k_tokens: supp tile now staged in LDS once per block
// (44KB), replacing 704 wave-uniform GLOBAL loads per block in the inner
// loop (latency-bound) with LDS broadcasts.
//
// Workspace layout (floats):
//   lbn_ws     [0,16384)             normalized basis, [g][c][k]
//   invden_ws  [16384,20480)         1/max(sum_p supp,1e-6) per (s,k)
//   presraw    [20480,24576)         unnormalized presence per (s,k)
//   supp_pk    [2908160,5791744)     supp, [s][p][k]  (tokens kernel)

#define C_ 256
#define W_ 44
#define P_ 704          // 16*44 positions per stripe
#define CH_STRIDE 2816  // 64*44
#define NB_STRIDE 720896 // 256*2816
#define TOPK_ 88
#define GATE_ 0.05f
#define EPS_ 1e-6f

// DPP wave-wide shifts: lane i <- lane i-1 (shr) / i+1 (shl), bound_ctrl
// zero-fills the edge lane. VALU pipe.
#define DPP_WAVE_SHL1 0x130
#define DPP_WAVE_SHR1 0x138
__device__ __forceinline__ float dpp_from_left(float v) {   // lane l gets v[l-1], lane0 -> 0
  return __int_as_float(__builtin_amdgcn_update_dpp(
      0, __float_as_int(v), DPP_WAVE_SHR1, 0xF, 0xF, true));
}
__device__ __forceinline__ float dpp_from_right(float v) {  // lane l gets v[l+1], lane63 -> 0
  return __int_as_float(__builtin_amdgcn_update_dpp(
      0, __float_as_int(v), DPP_WAVE_SHL1, 0xF, 0xF, true));
}

// ---------------- kernel A: normalize latent basis ----------------
__global__ __launch_bounds__(256) void k_norm_basis(const float* __restrict__ lb,
                                                    float* __restrict__ lbn) {
  int gk = blockIdx.x;           // g*16+k
  int t = threadIdx.x;           // channel
  float v = lb[gk * 256 + t];
  float ss = v * v;
  #pragma unroll
  for (int off = 32; off >= 1; off >>= 1) ss += __shfl_xor(ss, off);
  __shared__ float red[4];
  if ((t & 63) == 0) red[t >> 6] = ss;
  __syncthreads();
  float tot = red[0] + red[1] + red[2] + red[3];
  float scale = 1.f / fmaxf(sqrtf(tot), 1e-12f);
  int g = gk >> 4, k = gk & 15;
  lbn[((g * 256 + t) << 4) + k] = v * scale;   // [g][c][k]
}

// ---------------- kernel B: MONOLITH routing (round-9 proven version) --------
// One block per stripe, 1024 threads, wave w = stripe row w, lanes 0..43
// active. Main loop: barrier-free, LDS-free (DPP horizontal exchange,
// basis via wave-uniform scalar loads), 2-deep ping-pong prefetch.
// Epilogue: 3x3 pool via LDS (linearity), energy gate, softmax, supp,
// invden, then fused exact top-88 per-wave radix select.
#define LOAD_GRP(Pm, P0, Pp, cbase)                                    \
  { _Pragma("unroll")                                                  \
    for (int j_ = 0; j_ < 4; j_++) {                                   \
      const size_t o_ = (size_t)((cbase) + j_) * CH_STRIDE;            \
      Pm[j_] = xm[o_]; P0[j_] = xb[o_]; Pp[j_] = xp[o_];               \
    } }

#define CONS_GRP(Pm, P0, Pp, cbase)                                    \
  { _Pragma("unroll")                                                  \
    for (int j_ = 0; j_ < 4; j_++) {                                   \
      float a  = act ? P0[j_] : 0.f;                                   \
      float am_ = (act && hm) ? Pm[j_] : 0.f;                          \
      float ap_ = (act && hp) ? Pp[j_] : 0.f;                          \
      float vs = am_ + a + ap_;                                        \
      float lf = dpp_from_left(vs);                                    \
      float rt = dpp_from_right(vs);                                   \
      float win = lf + vs + rt;                                        \
      pw2 = fmaf(win, win, pw2);                                       \
      sq  = fmaf(a, a, sq);                                            \
      const int co_ = __builtin_amdgcn_readfirstlane(((cbase) + j_) << 4); \
      const float4* wp4 = (const float4*)(lbb + co_);                  \
      float4 w0 = wp4[0], w1 = wp4[1], w2 = wp4[2], w3 = wp4[3];       \
      rawdot[0]  = fmaf(a, w0.x, rawdot[0]);  rawdot[1]  = fmaf(a, w0.y, rawdot[1]);  \
      rawdot[2]  = fmaf(a, w0.z, rawdot[2]);  rawdot[3]  = fmaf(a, w0.w, rawdot[3]);  \
      rawdot[4]  = fmaf(a, w1.x, rawdot[4]);  rawdot[5]  = fmaf(a, w1.y, rawdot[5]);  \
      rawdot[6]  = fmaf(a, w1.z, rawdot[6]);  rawdot[7]  = fmaf(a, w1.w, rawdot[7]);  \
      rawdot[8]  = fmaf(a, w2.x, rawdot[8]);  rawdot[9]  = fmaf(a, w2.y, rawdot[9]);  \
      rawdot[10] = fmaf(a, w2.z, rawdot[10]); rawdot[11] = fmaf(a, w2.w, rawdot[11]); \
      rawdot[12] = fmaf(a, w3.x, rawdot[12]); rawdot[13] = fmaf(a, w3.y, rawdot[13]); \
      rawdot[14] = fmaf(a, w3.z, rawdot[14]); rawdot[15] = fmaf(a, w3.w, rawdot[15]); \
    } }

__global__ __launch_bounds__(1024, 4) void k_route(const float* __restrict__ x,
                                                   const float* __restrict__ lbn,
                                                   float* __restrict__ supp_pk,
                                                   float* __restrict__ invden_ws,
                                                   float* __restrict__ presraw) {
  __shared__ float rsl[11264];          // rawdot [k][704], then supp [k][704]; 44 KB
  __shared__ uint32_t hist_l[16 * 256]; // per-wave radix histograms, 16 KB
  __shared__ float redA[16];
  __shared__ float redB[16];
  __shared__ float redM[2];
  __shared__ float red2[16 * 16];

  const int tid = threadIdx.x;
  const int w = tid >> 6;          // row
  const int l = tid & 63;          // col
  const bool act = (l < 44);
  const int s = blockIdx.x, n = s >> 2, g = s & 3;
  const int p = w * 44 + l;

  const int lsafe = act ? l : 0;   // address clamp
  const float* xb = x + (size_t)n * NB_STRIDE + (g * 16 + w) * 44 + lsafe;
  const float* xm = xb + ((w > 0)  ? -44 : 0);   // clamped row addresses
  const float* xp = xb + ((w < 15) ?  44 : 0);
  const bool hm = (w > 0), hp = (w < 15);

  // wave-uniform basis base for this group: 256ch x 16k slice
  const float* lbb = lbn + (g << 12);

  float rawdot[16];
  #pragma unroll
  for (int k = 0; k < 16; k++) rawdot[k] = 0.f;
  float sq = 0.f, pw2 = 0.f;

  float Avm[4], Av0[4], Avp[4];
  float Bvm[4], Bv0[4], Bvp[4];

  LOAD_GRP(Avm, Av0, Avp, 0)
  for (int c = 0; c < 256; c += 8) {
    LOAD_GRP(Bvm, Bv0, Bvp, c + 4)
    CONS_GRP(Avm, Av0, Avp, c)
    if (c + 8 < 256) { LOAD_GRP(Avm, Av0, Avp, c + 8) }
    CONS_GRP(Bvm, Bv0, Bvp, c + 4)
  }

  // ---- epilogue: pool, gate, softmax, supp, invden, fused topk ----
  if (act) {
    #pragma unroll
    for (int k = 0; k < 16; k++) rsl[k * 704 + p] = rawdot[k];
  }
  __syncthreads();   // rsl ready

  // 3x3 pool of rawdot (linearity: pool(raw).basis == pool(raw.basis))
  float pd[16];
  #pragma unroll
  for (int k = 0; k < 16; k++) pd[k] = 0.f;
  if (act) {
    #pragma unroll
    for (int dy = -1; dy <= 1; dy++) {
      int yy = w + dy;
      if (yy < 0 || yy > 15) continue;
      #pragma unroll
      for (int dx = -1; dx <= 1; dx++) {
        int xx = l + dx;
        if (xx < 0 || xx > 43) continue;
        int pp = yy * 44 + xx;
        #pragma unroll
        for (int k = 0; k < 16; k++) pd[k] += rsl[k * 704 + pp];
      }
    }
  }

  // stripe-wide energy max
  float e_raw = sq * (1.f / 256.f);            // inactive lanes: 0
  float m = e_raw;
  #pragma unroll
  for (int off = 32; off >= 1; off >>= 1) m = fmaxf(m, __shfl_xor(m, off));
  if (l == 0) redA[w] = m;
  __syncthreads();                             // (also: all rsl pool-reads done)
  if (tid == 0) {
    float mm = redA[0];
    for (int w2 = 1; w2 < 16; w2++) mm = fmaxf(mm, redA[w2]);
    redM[0] = mm;
  }
  __syncthreads();
  float M = fmaxf(redM[0], EPS_);
  float e = e_raw / M;
  float am = (e > GATE_) ? 1.f : 0.f;
  float fb = (e_raw > 0.f) ? 1.f : 0.f;
  float a = am;
  #pragma unroll
  for (int off = 32; off >= 1; off >>= 1) a += __shfl_xor(a, off);
  if (l == 0) redB[w] = a;
  __syncthreads();
  if (tid == 0) {
    float sm = 0.f;
    for (int w2 = 0; w2 < 16; w2++) sm += redB[w2];
    redM[1] = sm;
  }
  __syncthreads();
  if (redM[1] <= 0.f) am = fb;

  float pnorm = sqrtf(pw2) * (1.f / 9.f);      // ||pooled||
  float invn = 1.f / fmaxf(pnorm, 1e-12f);
  float scl = invn * (8.f / 9.f);              // /9 pool, /0.125 temp
  float li[16];
  float mx = -1e30f;
  #pragma unroll
  for (int k = 0; k < 16; k++) { li[k] = pd[k] * scl; mx = fmaxf(mx, li[k]); }
  float ssum = 0.f;
  #pragma unroll
  for (int k = 0; k < 16; k++) { li[k] = __expf(li[k] - mx); ssum += li[k]; }
  float rs2 = am / ssum;
  float supp[16];
  #pragma unroll
  for (int k = 0; k < 16; k++) supp[k] = li[k] * rs2;

  // global supp in [p][k] layout for k_tokens
  if (act) {
    float* spk = supp_pk + ((size_t)s * 704 + p) * 16;
    #pragma unroll
    for (int kq = 0; kq < 4; kq++)
      ((float4*)spk)[kq] = make_float4(supp[kq*4+0], supp[kq*4+1],
                                       supp[kq*4+2], supp[kq*4+3]);
  }

  // per-k denominators (inactive lanes contribute 0)
  #pragma unroll
  for (int k = 0; k < 16; k++) {
    float v2 = act ? supp[k] : 0.f;
    #pragma unroll
    for (int off = 32; off >= 1; off >>= 1) v2 += __shfl_xor(v2, off);
    if (l == 0) red2[w * 16 + k] = v2;
  }
  __syncthreads();
  if (tid < 16) {
    float den = 0.f;
    for (int w2 = 0; w2 < 16; w2++) den += red2[w2 * 16 + tid];
    invden_ws[s * 16 + tid] = 1.f / fmaxf(den, EPS_);
  }

  // ---- fused exact top-88 mean (per-wave radix select) ----
  // overwrite rsl with supp [k][704] (all pool reads completed before the
  // redA barrier above)
  if (act) {
    #pragma unroll
    for (int k = 0; k < 16; k++) rsl[k * 704 + p] = supp[k];
  }
  __syncthreads();   // supp in LDS visible to all waves

  {
    const int k = w;               // wave w owns latent k
    uint32_t key[11];
    #pragma unroll
    for (int j = 0; j < 11; j++)
      key[j] = __float_as_uint(rsl[k * 704 + l + 64 * j]);  // supp>=0 -> monotone bits
    uint32_t* h = &hist_l[w * 256];
    uint32_t prefix = 0, remaining = TOPK_;
    #pragma unroll
    for (int b = 3; b >= 0; b--) {
      const int shift = b * 8;
      *(uint4*)&h[l * 4] = make_uint4(0u, 0u, 0u, 0u);
      uint32_t mhi = (b == 3) ? 0u : (0xFFFFFFFFu << (shift + 8));
      #pragma unroll
      for (int j = 0; j < 11; j++)
        if ((key[j] & mhi) == (prefix & mhi))
          atomicAdd(&h[(key[j] >> shift) & 255u], 1u);
      uint4 bn = *(uint4*)&h[l * 4];
      uint32_t T = bn.x + bn.y + bn.z + bn.w;
      uint32_t inc = T;
      #pragma unroll
      for (int off = 1; off < 64; off <<= 1) {
        uint32_t o = (uint32_t)__shfl_down((int)inc, off);
        if (l + off < 64) inc += o;
      }                              // inc = sum over lanes >= l
      uint32_t excl = inc - T;       // lanes > l
      uint32_t g3 = excl + bn.w, g2 = g3 + bn.z, g1 = g2 + bn.y, g0 = g1 + bn.x;
      uint32_t pk = 0u;
      if (g0 >= remaining && g1 < remaining) pk = ((uint32_t)(4*l+0) << 16) | (remaining - g1);
      if (g1 >= remaining && g2 < remaining) pk = ((uint32_t)(4*l+1) << 16) | (remaining - g2);
      if (g2 >= remaining && g3 < remaining) pk = ((uint32_t)(4*l+2) << 16) | (remaining - g3);
      if (g3 >= remaining && excl < remaining) pk = ((uint32_t)(4*l+3) << 16) | (remaining - excl);
      #pragma unroll
      for (int off = 32; off >= 1; off >>= 1) pk |= (uint32_t)__shfl_xor((int)pk, off);
      prefix |= ((pk >> 16) & 255u) << shift;
      remaining = pk & 0xFFFFu;
    }
    float tf = __uint_as_float(prefix);
    float sgt = 0.f; uint32_t cgt = 0u;
    #pragma unroll
    for (int j = 0; j < 11; j++)
      if (key[j] > prefix) { sgt += __uint_as_float(key[j]); cgt++; }
    #pragma unroll
    for (int off = 32; off >= 1; off >>= 1) {
      sgt += __shfl_xor(sgt, off);
      cgt += (uint32_t)__shfl_xor((int)cgt, off);
    }
    if (l == 0)
      presraw[s * 16 + k] = (sgt + (float)(TOPK_ - cgt) * tf) * (1.f / (float)TOPK_);
  }
}

// ---------------- kernel 3: tokens GEMM, supp staged in LDS ----------------
// Round-14: the inner loop previously issued 704 wave-uniform GLOBAL loads
// of supp per block (serialized broadcast latency against 44 barriers).
// supp tile (704x16 = 44KB) is now staged into LDS once per block; inner
// loop reads it via uniform-address LDS broadcast. x path unchanged.
// 60KB LDS/block, 2 blocks/CU at __launch_bounds__(512,4).
__global__ __launch_bounds__(512, 4) void k_tokens(const float* __restrict__ x,
                                                   const float* __restrict__ supp_pk,
                                                   const float* __restrict__ invden,
                                                   float* __restrict__ out) {
  __shared__ float xl[4096];   // 128ch x 32pos; reused for quarter-reduce
  __shared__ float sl[11264];  // supp [p][k] for this stripe, 44 KB
  const int tid = threadIdx.x;
  const int bid = blockIdx.x;
  const int s = bid >> 1, chalf = bid & 1;
  const int n = s >> 2, g = s & 3;
  const int cl = tid & 127;               // local channel
  const int q = tid >> 7;                 // position quarter (wave-uniform)

  const float* xs = x + (size_t)n * NB_STRIDE + (size_t)(chalf * 128) * CH_STRIDE + g * P_;

  const int li0 = tid, li1 = tid + 512;
  const int lc0 = li0 >> 3, lj0 = li0 & 7;
  const int lc1 = li1 >> 3, lj1 = li1 & 7;
  const float* gp0 = xs + (size_t)lc0 * CH_STRIDE + lj0 * 4;
  const float* gp1 = xs + (size_t)lc1 * CH_STRIDE + lj1 * 4;
  const int wo0 = lc0 * 32 + ((lj0 * 4) ^ ((lc0 & 7) * 4));
  const int wo1 = lc1 * 32 + ((lj1 * 4) ^ ((lc1 & 7) * 4));

  const int sw = (cl & 7) * 4;
  const int rbase = cl * 32;

  float acc[16];
  #pragma unroll
  for (int k = 0; k < 16; k++) acc[k] = 0.f;

  // stage supp tile (2816 float4) + first x tile, one barrier
  {
    const float4* ssrc = (const float4*)(supp_pk + (size_t)s * 11264);
    float4* sdst = (float4*)sl;
    #pragma unroll
    for (int i = 0; i < 6; i++) {
      int idx = tid + i * 512;
      if (idx < 2816) sdst[idx] = ssrc[idx];
    }
  }
  float4 r0 = *(const float4*)gp0;
  float4 r1 = *(const float4*)gp1;
  *(float4*)&xl[wo0] = r0;
  *(float4*)&xl[wo1] = r1;
  __syncthreads();

  for (int tt = 0; tt < 22; tt++) {
    const int p0 = tt * 32;
    float4 n0, n1;
    if (tt < 21) {
      n0 = *(const float4*)(gp0 + p0 + 32);
      n1 = *(const float4*)(gp1 + p0 + 32);
    }

    #pragma unroll
    for (int jj = 0; jj < 8; jj += 4) {
      const int pp0 = q * 8 + jj;
      float4 xv = *(const float4*)&xl[rbase + (pp0 ^ sw)];
      float xa[4] = {xv.x, xv.y, xv.z, xv.w};
      #pragma unroll
      for (int dj = 0; dj < 4; dj++) {
        const float4* sp = (const float4*)&sl[(p0 + pp0 + dj) * 16];
        float4 s0 = sp[0], s1 = sp[1], s2 = sp[2], s3 = sp[3];
        float a = xa[dj];
        acc[0]  += a * s0.x; acc[1]  += a * s0.y; acc[2]  += a * s0.z; acc[3]  += a * s0.w;
        acc[4]  += a * s1.x; acc[5]  += a * s1.y; acc[6]  += a * s1.z; acc[7]  += a * s1.w;
        acc[8]  += a * s2.x; acc[9]  += a * s2.y; acc[10] += a * s2.z; acc[11] += a * s2.w;
        acc[12] += a * s3.x; acc[13] += a * s3.y; acc[14] += a * s3.z; acc[15] += a * s3.w;
      }
    }

    __syncthreads();
    if (tt < 21) {
      *(float4*)&xl[wo0] = n0;
      *(float4*)&xl[wo1] = n1;
      __syncthreads();
    }
  }

  // quarter-reduce via LDS (xl reused)
  if (q >= 2) {
    float* dst = &xl[((q - 2) * 128 + cl) * 16];
    #pragma unroll
    for (int kq = 0; kq < 4; kq++)
      ((float4*)dst)[kq] = make_float4(acc[kq*4], acc[kq*4+1], acc[kq*4+2], acc[kq*4+3]);
  }
  __syncthreads();
  if (q < 2) {
    const float* src = &xl[(q * 128 + cl) * 16];
    #pragma unroll
    for (int k = 0; k < 16; k++) acc[k] += src[k];
  }
  __syncthreads();
  if (q == 1) {
    float* dst = &xl[cl * 16];
    #pragma unroll
    for (int kq = 0; kq < 4; kq++)
      ((float4*)dst)[kq] = make_float4(acc[kq*4], acc[kq*4+1], acc[kq*4+2], acc[kq*4+3]);
  }
  __syncthreads();
  if (q == 0) {
    const float* src = &xl[cl * 16];
    float* op = out + ((size_t)(n * 256 + chalf * 128 + cl) * 64) + g * 16;
    #pragma unroll
    for (int kq = 0; kq < 4; kq++) {
      int u = __builtin_amdgcn_readfirstlane(s * 16 + kq * 4);
      const float4 iv = *(const float4*)(invden + u);
      float4 o;
      o.x = (acc[kq*4+0] + src[kq*4+0]) * iv.x;
      o.y = (acc[kq*4+1] + src[kq*4+1]) * iv.y;
      o.z = (acc[kq*4+2] + src[kq*4+2]) * iv.z;
      o.w = (acc[kq*4+3] + src[kq*4+3]) * iv.w;
      ((float4*)op)[kq] = o;
    }
  }
}

// ---------------- kernel D: presence normalization ----------------
__global__ __launch_bounds__(64) void k_pres(const float* __restrict__ presraw,
                                             float* __restrict__ out) {
  const int n = blockIdx.x, t = threadIdx.x;
  float v = presraw[n * 64 + t];
  float ssum = v;
  #pragma unroll
  for (int off = 32; off >= 1; off >>= 1) ssum += __shfl_xor(ssum, off);
  out[1048576 + n * 64 + t] = v / fmaxf(ssum, EPS_);
}

extern "C" void kernel_launch(void* const* d_in, const int* in_sizes, int n_in,
                              void* d_out, int out_size, void* d_ws, size_t ws_size,
                              hipStream_t stream) {
  (void)in_sizes; (void)n_in; (void)out_size; (void)ws_size;
  const float* x  = (const float*)d_in[0];
  const float* lb = (const float*)d_in[1];
  float* out = (float*)d_out;
  float* ws = (float*)d_ws;
  float* lbn_ws     = ws;              // 16384 floats
  float* invden_ws  = ws + 16384;      // 4096
  float* presraw_ws = ws + 20480;      // 4096
  float* supp_pk_ws = ws + 2908160;    // 2883584, supp [s][p][k]

  k_norm_basis<<<64, 256, 0, stream>>>(lb, lbn_ws);
  k_route<<<256, 1024, 0, stream>>>(x, lbn_ws, supp_pk_ws, invden_ws, presraw_ws);
  k_tokens<<<512, 512, 0, stream>>>(x, supp_pk_ws, invden_ws, out);
  k_pres<<<64, 64, 0, stream>>>(presraw_ws, out);
}

// Round 12
// 329.989 us; speedup vs baseline: 1.7190x; 1.0011x over previous
//
#include <hip/hip_runtime.h>
#include <cstdint>

// LatentFactorPooling on MI355X.
// x: (64,256,64,44) fp32, basis: (4,16,256) fp32.
// out: tokens (64,256,64) fp32 then pres (64,64) fp32.
//
// Round-15: k_tokens split by position-half (352 pos per block, 11 exact
// 32-pos tiles). LDS 60->39KB, blocks/CU 2->4 (32 waves = 100% occupancy),
// barriers/block 44->22. Partial (c,k) sums -> workspace; k_tok_red sums
// halves * invden. k_route = round-9 proven monolith (108us), untouched.
//
// Workspace layout (floats):
//   lbn_ws     [0,16384)             normalized basis, [g][c][k]
//   invden_ws  [16384,20480)         1/max(sum_p supp,1e-6) per (s,k)
//   presraw    [20480,24576)         unnormalized presence per (s,k)
//   partials   [24576,2121728)       tokens partials [s][chalf][ph][128c][16k]
//   supp_pk    [2908160,5791744)     supp, [s][p][k]  (tokens kernel)

#define C_ 256
#define W_ 44
#define P_ 704          // 16*44 positions per stripe
#define CH_STRIDE 2816  // 64*44
#define NB_STRIDE 720896 // 256*2816
#define TOPK_ 88
#define GATE_ 0.05f
#define EPS_ 1e-6f

// DPP wave-wide shifts: lane i <- lane i-1 (shr) / i+1 (shl), bound_ctrl
// zero-fills the edge lane. VALU pipe.
#define DPP_WAVE_SHL1 0x130
#define DPP_WAVE_SHR1 0x138
__device__ __forceinline__ float dpp_from_left(float v) {   // lane l gets v[l-1], lane0 -> 0
  return __int_as_float(__builtin_amdgcn_update_dpp(
      0, __float_as_int(v), DPP_WAVE_SHR1, 0xF, 0xF, true));
}
__device__ __forceinline__ float dpp_from_right(float v) {  // lane l gets v[l+1], lane63 -> 0
  return __int_as_float(__builtin_amdgcn_update_dpp(
      0, __float_as_int(v), DPP_WAVE_SHL1, 0xF, 0xF, true));
}

// ---------------- kernel A: normalize latent basis ----------------
__global__ __launch_bounds__(256) void k_norm_basis(const float* __restrict__ lb,
                                                    float* __restrict__ lbn) {
  int gk = blockIdx.x;           // g*16+k
  int t = threadIdx.x;           // channel
  float v = lb[gk * 256 + t];
  float ss = v * v;
  #pragma unroll
  for (int off = 32; off >= 1; off >>= 1) ss += __shfl_xor(ss, off);
  __shared__ float red[4];
  if ((t & 63) == 0) red[t >> 6] = ss;
  __syncthreads();
  float tot = red[0] + red[1] + red[2] + red[3];
  float scale = 1.f / fmaxf(sqrtf(tot), 1e-12f);
  int g = gk >> 4, k = gk & 15;
  lbn[((g * 256 + t) << 4) + k] = v * scale;   // [g][c][k]
}

// ---------------- kernel B: MONOLITH routing (round-9 proven version) --------
#define LOAD_GRP(Pm, P0, Pp, cbase)                                    \
  { _Pragma("unroll")                                                  \
    for (int j_ = 0; j_ < 4; j_++) {                                   \
      const size_t o_ = (size_t)((cbase) + j_) * CH_STRIDE;            \
      Pm[j_] = xm[o_]; P0[j_] = xb[o_]; Pp[j_] = xp[o_];               \
    } }

#define CONS_GRP(Pm, P0, Pp, cbase)                                    \
  { _Pragma("unroll")                                                  \
    for (int j_ = 0; j_ < 4; j_++) {                                   \
      float a  = act ? P0[j_] : 0.f;                                   \
      float am_ = (act && hm) ? Pm[j_] : 0.f;                          \
      float ap_ = (act && hp) ? Pp[j_] : 0.f;                          \
      float vs = am_ + a + ap_;                                        \
      float lf = dpp_from_left(vs);                                    \
      float rt = dpp_from_right(vs);                                   \
      float win = lf + vs + rt;                                        \
      pw2 = fmaf(win, win, pw2);                                       \
      sq  = fmaf(a, a, sq);                                            \
      const int co_ = __builtin_amdgcn_readfirstlane(((cbase) + j_) << 4); \
      const float4* wp4 = (const float4*)(lbb + co_);                  \
      float4 w0 = wp4[0], w1 = wp4[1], w2 = wp4[2], w3 = wp4[3];       \
      rawdot[0]  = fmaf(a, w0.x, rawdot[0]);  rawdot[1]  = fmaf(a, w0.y, rawdot[1]);  \
      rawdot[2]  = fmaf(a, w0.z, rawdot[2]);  rawdot[3]  = fmaf(a, w0.w, rawdot[3]);  \
      rawdot[4]  = fmaf(a, w1.x, rawdot[4]);  rawdot[5]  = fmaf(a, w1.y, rawdot[5]);  \
      rawdot[6]  = fmaf(a, w1.z, rawdot[6]);  rawdot[7]  = fmaf(a, w1.w, rawdot[7]);  \
      rawdot[8]  = fmaf(a, w2.x, rawdot[8]);  rawdot[9]  = fmaf(a, w2.y, rawdot[9]);  \
      rawdot[10] = fmaf(a, w2.z, rawdot[10]); rawdot[11] = fmaf(a, w2.w, rawdot[11]); \
      rawdot[12] = fmaf(a, w3.x, rawdot[12]); rawdot[13] = fmaf(a, w3.y, rawdot[13]); \
      rawdot[14] = fmaf(a, w3.z, rawdot[14]); rawdot[15] = fmaf(a, w3.w, rawdot[15]); \
    } }

__global__ __launch_bounds__(1024, 4) void k_route(const float* __restrict__ x,
                                                   const float* __restrict__ lbn,
                                                   float* __restrict__ supp_pk,
                                                   float* __restrict__ invden_ws,
                                                   float* __restrict__ presraw) {
  __shared__ float rsl[11264];          // rawdot [k][704], then supp [k][704]; 44 KB
  __shared__ uint32_t hist_l[16 * 256]; // per-wave radix histograms, 16 KB
  __shared__ float redA[16];
  __shared__ float redB[16];
  __shared__ float redM[2];
  __shared__ float red2[16 * 16];

  const int tid = threadIdx.x;
  const int w = tid >> 6;          // row
  const int l = tid & 63;          // col
  const bool act = (l < 44);
  const int s = blockIdx.x, n = s >> 2, g = s & 3;
  const int p = w * 44 + l;

  const int lsafe = act ? l : 0;   // address clamp
  const float* xb = x + (size_t)n * NB_STRIDE + (g * 16 + w) * 44 + lsafe;
  const float* xm = xb + ((w > 0)  ? -44 : 0);   // clamped row addresses
  const float* xp = xb + ((w < 15) ?  44 : 0);
  const bool hm = (w > 0), hp = (w < 15);

  // wave-uniform basis base for this group: 256ch x 16k slice
  const float* lbb = lbn + (g << 12);

  float rawdot[16];
  #pragma unroll
  for (int k = 0; k < 16; k++) rawdot[k] = 0.f;
  float sq = 0.f, pw2 = 0.f;

  float Avm[4], Av0[4], Avp[4];
  float Bvm[4], Bv0[4], Bvp[4];

  LOAD_GRP(Avm, Av0, Avp, 0)
  for (int c = 0; c < 256; c += 8) {
    LOAD_GRP(Bvm, Bv0, Bvp, c + 4)
    CONS_GRP(Avm, Av0, Avp, c)
    if (c + 8 < 256) { LOAD_GRP(Avm, Av0, Avp, c + 8) }
    CONS_GRP(Bvm, Bv0, Bvp, c + 4)
  }

  // ---- epilogue: pool, gate, softmax, supp, invden, fused topk ----
  if (act) {
    #pragma unroll
    for (int k = 0; k < 16; k++) rsl[k * 704 + p] = rawdot[k];
  }
  __syncthreads();   // rsl ready

  // 3x3 pool of rawdot (linearity: pool(raw).basis == pool(raw.basis))
  float pd[16];
  #pragma unroll
  for (int k = 0; k < 16; k++) pd[k] = 0.f;
  if (act) {
    #pragma unroll
    for (int dy = -1; dy <= 1; dy++) {
      int yy = w + dy;
      if (yy < 0 || yy > 15) continue;
      #pragma unroll
      for (int dx = -1; dx <= 1; dx++) {
        int xx = l + dx;
        if (xx < 0 || xx > 43) continue;
        int pp = yy * 44 + xx;
        #pragma unroll
        for (int k = 0; k < 16; k++) pd[k] += rsl[k * 704 + pp];
      }
    }
  }

  // stripe-wide energy max
  float e_raw = sq * (1.f / 256.f);            // inactive lanes: 0
  float m = e_raw;
  #pragma unroll
  for (int off = 32; off >= 1; off >>= 1) m = fmaxf(m, __shfl_xor(m, off));
  if (l == 0) redA[w] = m;
  __syncthreads();                             // (also: all rsl pool-reads done)
  if (tid == 0) {
    float mm = redA[0];
    for (int w2 = 1; w2 < 16; w2++) mm = fmaxf(mm, redA[w2]);
    redM[0] = mm;
  }
  __syncthreads();
  float M = fmaxf(redM[0], EPS_);
  float e = e_raw / M;
  float am = (e > GATE_) ? 1.f : 0.f;
  float fb = (e_raw > 0.f) ? 1.f : 0.f;
  float a = am;
  #pragma unroll
  for (int off = 32; off >= 1; off >>= 1) a += __shfl_xor(a, off);
  if (l == 0) redB[w] = a;
  __syncthreads();
  if (tid == 0) {
    float sm = 0.f;
    for (int w2 = 0; w2 < 16; w2++) sm += redB[w2];
    redM[1] = sm;
  }
  __syncthreads();
  if (redM[1] <= 0.f) am = fb;

  float pnorm = sqrtf(pw2) * (1.f / 9.f);      // ||pooled||
  float invn = 1.f / fmaxf(pnorm, 1e-12f);
  float scl = invn * (8.f / 9.f);              // /9 pool, /0.125 temp
  float li[16];
  float mx = -1e30f;
  #pragma unroll
  for (int k = 0; k < 16; k++) { li[k] = pd[k] * scl; mx = fmaxf(mx, li[k]); }
  float ssum = 0.f;
  #pragma unroll
  for (int k = 0; k < 16; k++) { li[k] = __expf(li[k] - mx); ssum += li[k]; }
  float rs2 = am / ssum;
  float supp[16];
  #pragma unroll
  for (int k = 0; k < 16; k++) supp[k] = li[k] * rs2;

  // global supp in [p][k] layout for k_tokens
  if (act) {
    float* spk = supp_pk + ((size_t)s * 704 + p) * 16;
    #pragma unroll
    for (int kq = 0; kq < 4; kq++)
      ((float4*)spk)[kq] = make_float4(supp[kq*4+0], supp[kq*4+1],
                                       supp[kq*4+2], supp[kq*4+3]);
  }

  // per-k denominators (inactive lanes contribute 0)
  #pragma unroll
  for (int k = 0; k < 16; k++) {
    float v2 = act ? supp[k] : 0.f;
    #pragma unroll
    for (int off = 32; off >= 1; off >>= 1) v2 += __shfl_xor(v2, off);
    if (l == 0) red2[w * 16 + k] = v2;
  }
  __syncthreads();
  if (tid < 16) {
    float den = 0.f;
    for (int w2 = 0; w2 < 16; w2++) den += red2[w2 * 16 + tid];
    invden_ws[s * 16 + tid] = 1.f / fmaxf(den, EPS_);
  }

  // ---- fused exact top-88 mean (per-wave radix select) ----
  if (act) {
    #pragma unroll
    for (int k = 0; k < 16; k++) rsl[k * 704 + p] = supp[k];
  }
  __syncthreads();   // supp in LDS visible to all waves

  {
    const int k = w;               // wave w owns latent k
    uint32_t key[11];
    #pragma unroll
    for (int j = 0; j < 11; j++)
      key[j] = __float_as_uint(rsl[k * 704 + l + 64 * j]);  // supp>=0 -> monotone bits
    uint32_t* h = &hist_l[w * 256];
    uint32_t prefix = 0, remaining = TOPK_;
    #pragma unroll
    for (int b = 3; b >= 0; b--) {
      const int shift = b * 8;
      *(uint4*)&h[l * 4] = make_uint4(0u, 0u, 0u, 0u);
      uint32_t mhi = (b == 3) ? 0u : (0xFFFFFFFFu << (shift + 8));
      #pragma unroll
      for (int j = 0; j < 11; j++)
        if ((key[j] & mhi) == (prefix & mhi))
          atomicAdd(&h[(key[j] >> shift) & 255u], 1u);
      uint4 bn = *(uint4*)&h[l * 4];
      uint32_t T = bn.x + bn.y + bn.z + bn.w;
      uint32_t inc = T;
      #pragma unroll
      for (int off = 1; off < 64; off <<= 1) {
        uint32_t o = (uint32_t)__shfl_down((int)inc, off);
        if (l + off < 64) inc += o;
      }                              // inc = sum over lanes >= l
      uint32_t excl = inc - T;       // lanes > l
      uint32_t g3 = excl + bn.w, g2 = g3 + bn.z, g1 = g2 + bn.y, g0 = g1 + bn.x;
      uint32_t pk = 0u;
      if (g0 >= remaining && g1 < remaining) pk = ((uint32_t)(4*l+0) << 16) | (remaining - g1);
      if (g1 >= remaining && g2 < remaining) pk = ((uint32_t)(4*l+1) << 16) | (remaining - g2);
      if (g2 >= remaining && g3 < remaining) pk = ((uint32_t)(4*l+2) << 16) | (remaining - g3);
      if (g3 >= remaining && excl < remaining) pk = ((uint32_t)(4*l+3) << 16) | (remaining - excl);
      #pragma unroll
      for (int off = 32; off >= 1; off >>= 1) pk |= (uint32_t)__shfl_xor((int)pk, off);
      prefix |= ((pk >> 16) & 255u) << shift;
      remaining = pk & 0xFFFFu;
    }
    float tf = __uint_as_float(prefix);
    float sgt = 0.f; uint32_t cgt = 0u;
    #pragma unroll
    for (int j = 0; j < 11; j++)
      if (key[j] > prefix) { sgt += __uint_as_float(key[j]); cgt++; }
    #pragma unroll
    for (int off = 32; off >= 1; off >>= 1) {
      sgt += __shfl_xor(sgt, off);
      cgt += (uint32_t)__shfl_xor((int)cgt, off);
    }
    if (l == 0)
      presraw[s * 16 + k] = (sgt + (float)(TOPK_ - cgt) * tf) * (1.f / (float)TOPK_);
  }
}

// ---------------- kernel 3: tokens GEMM, position-split (4 blocks/stripe) ----
// Round-15: each block handles 352 positions (11 exact 32-pos tiles) of one
// (stripe, chalf). LDS 39KB -> 4 blocks/CU = 32 waves (100% occupancy),
// 22 barriers/block (was 44). Writes PARTIAL (128c x 16k) sums; k_tok_red
// combines the two position-halves and applies invden.
__global__ __launch_bounds__(512, 4) void k_tokens(const float* __restrict__ x,
                                                   const float* __restrict__ supp_pk,
                                                   float* __restrict__ partials) {
  __shared__ float xl[4096];   // 128ch x 32pos; reused for quarter-reduce
  __shared__ float sl[5632];   // supp [352][16] for this half, 22 KB
  const int tid = threadIdx.x;
  const int bid = blockIdx.x;
  const int s = bid >> 2;
  const int chalf = (bid >> 1) & 1;
  const int ph = bid & 1;                 // position half: 0 -> p 0..351, 1 -> 352..703
  const int n = s >> 2, g = s & 3;
  const int cl = tid & 127;               // local channel
  const int q = tid >> 7;                 // position quarter (wave-uniform)

  const float* xs = x + (size_t)n * NB_STRIDE + (size_t)(chalf * 128) * CH_STRIDE
                      + g * P_ + ph * 352;

  const int li0 = tid, li1 = tid + 512;
  const int lc0 = li0 >> 3, lj0 = li0 & 7;
  const int lc1 = li1 >> 3, lj1 = li1 & 7;
  const float* gp0 = xs + (size_t)lc0 * CH_STRIDE + lj0 * 4;
  const float* gp1 = xs + (size_t)lc1 * CH_STRIDE + lj1 * 4;
  const int wo0 = lc0 * 32 + ((lj0 * 4) ^ ((lc0 & 7) * 4));
  const int wo1 = lc1 * 32 + ((lj1 * 4) ^ ((lc1 & 7) * 4));

  const int sw = (cl & 7) * 4;
  const int rbase = cl * 32;

  float acc[16];
  #pragma unroll
  for (int k = 0; k < 16; k++) acc[k] = 0.f;

  // stage supp half-tile (1408 float4) + first x tile, one barrier
  {
    const float4* ssrc = (const float4*)(supp_pk + (size_t)s * 11264 + ph * 5632);
    float4* sdst = (float4*)sl;
    #pragma unroll
    for (int i = 0; i < 3; i++) {
      int idx = tid + i * 512;
      if (idx < 1408) sdst[idx] = ssrc[idx];
    }
  }
  float4 r0 = *(const float4*)gp0;
  float4 r1 = *(const float4*)gp1;
  *(float4*)&xl[wo0] = r0;
  *(float4*)&xl[wo1] = r1;
  __syncthreads();

  for (int tt = 0; tt < 11; tt++) {
    const int p0 = tt * 32;
    float4 n0, n1;
    if (tt < 10) {
      n0 = *(const float4*)(gp0 + p0 + 32);
      n1 = *(const float4*)(gp1 + p0 + 32);
    }

    #pragma unroll
    for (int jj = 0; jj < 8; jj += 4) {
      const int pp0 = q * 8 + jj;
      float4 xv = *(const float4*)&xl[rbase + (pp0 ^ sw)];
      float xa[4] = {xv.x, xv.y, xv.z, xv.w};
      #pragma unroll
      for (int dj = 0; dj < 4; dj++) {
        const float4* sp = (const float4*)&sl[(p0 + pp0 + dj) * 16];
        float4 s0 = sp[0], s1 = sp[1], s2 = sp[2], s3 = sp[3];
        float a = xa[dj];
        acc[0]  += a * s0.x; acc[1]  += a * s0.y; acc[2]  += a * s0.z; acc[3]  += a * s0.w;
        acc[4]  += a * s1.x; acc[5]  += a * s1.y; acc[6]  += a * s1.z; acc[7]  += a * s1.w;
        acc[8]  += a * s2.x; acc[9]  += a * s2.y; acc[10] += a * s2.z; acc[11] += a * s2.w;
        acc[12] += a * s3.x; acc[13] += a * s3.y; acc[14] += a * s3.z; acc[15] += a * s3.w;
      }
    }

    __syncthreads();
    if (tt < 10) {
      *(float4*)&xl[wo0] = n0;
      *(float4*)&xl[wo1] = n1;
      __syncthreads();
    }
  }

  // quarter-reduce via LDS (xl reused)
  if (q >= 2) {
    float* dst = &xl[((q - 2) * 128 + cl) * 16];
    #pragma unroll
    for (int kq = 0; kq < 4; kq++)
      ((float4*)dst)[kq] = make_float4(acc[kq*4], acc[kq*4+1], acc[kq*4+2], acc[kq*4+3]);
  }
  __syncthreads();
  if (q < 2) {
    const float* src = &xl[(q * 128 + cl) * 16];
    #pragma unroll
    for (int k = 0; k < 16; k++) acc[k] += src[k];
  }
  __syncthreads();
  if (q == 1) {
    float* dst = &xl[cl * 16];
    #pragma unroll
    for (int kq = 0; kq < 4; kq++)
      ((float4*)dst)[kq] = make_float4(acc[kq*4], acc[kq*4+1], acc[kq*4+2], acc[kq*4+3]);
  }
  __syncthreads();
  if (q == 0) {
    const float* src = &xl[cl * 16];
    float* op = partials + ((size_t)((s * 2 + chalf) * 2 + ph)) * 2048 + cl * 16;
    #pragma unroll
    for (int kq = 0; kq < 4; kq++) {
      float4 o;
      o.x = acc[kq*4+0] + src[kq*4+0];
      o.y = acc[kq*4+1] + src[kq*4+1];
      o.z = acc[kq*4+2] + src[kq*4+2];
      o.w = acc[kq*4+3] + src[kq*4+3];
      ((float4*)op)[kq] = o;
    }
  }
}

// ---------------- kernel 3b: combine position-halves, apply invden ----------
__global__ __launch_bounds__(256) void k_tok_red(const float* __restrict__ partials,
                                                 const float* __restrict__ invden,
                                                 float* __restrict__ out) {
  const int o4 = blockIdx.x * 256 + threadIdx.x;   // 0..262143
  const int f = o4 * 4;                            // out float index
  const int n = f >> 14;                           // / (256*64)
  const int ch = (f >> 6) & 255;
  const int r = f & 63;
  const int g = r >> 4, k0 = r & 15;               // k0 in {0,4,8,12}
  const int s = n * 4 + g;
  const int chalf = ch >> 7, cl = ch & 127;
  const size_t b0 = ((size_t)((s * 2 + chalf) * 2 + 0)) * 2048 + cl * 16 + k0;
  const float4 p0 = *(const float4*)(partials + b0);
  const float4 p1 = *(const float4*)(partials + b0 + 2048);
  const float4 iv = *(const float4*)(invden + s * 16 + k0);
  float4 o;
  o.x = (p0.x + p1.x) * iv.x;
  o.y = (p0.y + p1.y) * iv.y;
  o.z = (p0.z + p1.z) * iv.z;
  o.w = (p0.w + p1.w) * iv.w;
  *(float4*)(out + f) = o;
}

// ---------------- kernel D: presence normalization ----------------
__global__ __launch_bounds__(64) void k_pres(const float* __restrict__ presraw,
                                             float* __restrict__ out) {
  const int n = blockIdx.x, t = threadIdx.x;
  float v = presraw[n * 64 + t];
  float ssum = v;
  #pragma unroll
  for (int off = 32; off >= 1; off >>= 1) ssum += __shfl_xor(ssum, off);
  out[1048576 + n * 64 + t] = v / fmaxf(ssum, EPS_);
}

extern "C" void kernel_launch(void* const* d_in, const int* in_sizes, int n_in,
                              void* d_out, int out_size, void* d_ws, size_t ws_size,
                              hipStream_t stream) {
  (void)in_sizes; (void)n_in; (void)out_size; (void)ws_size;
  const float* x  = (const float*)d_in[0];
  const float* lb = (const float*)d_in[1];
  float* out = (float*)d_out;
  float* ws = (float*)d_ws;
  float* lbn_ws     = ws;              // 16384 floats
  float* invden_ws  = ws + 16384;      // 4096
  float* presraw_ws = ws + 20480;      // 4096
  float* partial_ws = ws + 24576;      // 2097152 floats (tokens partials)
  float* supp_pk_ws = ws + 2908160;    // 2883584, supp [s][p][k]

  k_norm_basis<<<64, 256, 0, stream>>>(lb, lbn_ws);
  k_route<<<256, 1024, 0, stream>>>(x, lbn_ws, supp_pk_ws, invden_ws, presraw_ws);
  k_tokens<<<1024, 512, 0, stream>>>(x, supp_pk_ws, partial_ws);
  k_tok_red<<<1024, 256, 0, stream>>>(partial_ws, invden_ws, out);
  k_pres<<<64, 64, 0, stream>>>(presraw_ws, out);
}